// Round 14
// baseline (42.427 us; speedup 1.0000x reference)
//
#include <hip/hip_runtime.h>

#define BT 256           // threads per block = 4 waves
#define JT 64            // j-tile width; each wave owns one 64-row i-tile
#define FARV 1.0e7f

__global__ __launch_bounds__(256) void ol_prep(
    const float* __restrict__ pos, const float* __restrict__ size,
    const float* __restrict__ valid, float4* __restrict__ A,
    int n, int total)
{
    int k = (int)blockIdx.x * 256 + (int)threadIdx.x;
    if (k >= total) return;
    float xj = FARV, yj = FARV, hwj = 0.f, hhj = 0.f;
    if (k < n) {
        float2 p = ((const float2*)pos)[k];
        float2 s = ((const float2*)size)[k];
        hwj = 0.5f * s.x;  hhj = 0.5f * s.y;
        if (valid[k] != 0.f) { xj = p.x; yj = p.y; }   // invalid -> FARV -> contributes 0
    }
    A[k] = make_float4(xj, yj, hwj, hhj);
}

template<bool DIAG>
__device__ __forceinline__ void inner_loop(
    const float4* __restrict__ Aj,       // wave-uniform (SGPR) base -> s_load_dwordx4
    int lane, float xi, float yi, float hwi, float hhi, float aie,
    float& s_iou, float& s_rep)
{
    const float EPSf = 1e-6f;
    #pragma unroll 8
    for (int t = 0; t < JT; ++t) {
        float4 a = Aj[t];                // uniform address: scalar load, SGPR operands

        float dx = xi - a.x;
        float dy = yi - a.y;
        if (DIAG) dx = (t > lane) ? dx : FARV;   // kills both terms for j<=i

        // 1-D overlap: (h1+h2) - max(|dx|, |h1-h2|), clamped at 0.
        float iw = fmaxf((hwi + a.z) - fmaxf(fabsf(dx), fabsf(hwi - a.z)), 0.f);
        float ih = fmaxf((hhi + a.w) - fmaxf(fabsf(dy), fabsf(hhi - a.w)), 0.f);
        float inter = iw * ih;
        // union = area_i + EPS + 4*hwj*hhj - inter
        float uni = fmaf(4.f * a.z, a.w, aie - inter);   // >= EPS
        float rc  = __builtin_amdgcn_rcpf(uni);
        s_iou = fmaf(inter, rc, s_iou);

        float d2 = fmaf(dx, dx, fmaf(dy, dy, EPSf));
        if (__any(d2 < 0.0036f)) {               // any lane within repel radius?
            float dist = __builtin_amdgcn_sqrtf(d2);
            float rp   = fmaxf(0.06f - dist, 0.f);
            s_rep = fmaf(rp, rp, s_rep);
        }
    }
}

__global__ __launch_bounds__(BT) void ol_pair_kernel(
    const float* __restrict__ pos, const float* __restrict__ size,
    const float* __restrict__ valid, const float4* __restrict__ A,
    float* __restrict__ part, int n, int Tj, int P)
{
    __shared__ float red_i[4], red_r[4];

    const float EPSf = 1e-6f;
    int tid  = (int)threadIdx.x;
    int lane = tid & 63;
    int wid  = tid >> 6;
    int bid  = (int)blockIdx.x;

    // Decode bid -> (IT, jt): i-group IT covers i-tiles 4IT..4IT+3, j-tiles jt >= 4IT.
    // C(r) = r*(Tj+2) - 2r^2 blocks precede group r.
    float Bf = (float)(Tj + 2);
    float disc = Bf * Bf - 8.f * (float)bid;
    int IT = (int)((Bf - sqrtf(fmaxf(disc, 0.f))) * 0.25f);
    IT = max(0, IT);
    while ((IT + 1) * (Tj + 2) - 2 * (IT + 1) * (IT + 1) <= bid) ++IT;
    while (IT > 0 && IT * (Tj + 2) - 2 * IT * IT > bid) --IT;
    // IT came through a float sqrt (VALU) -> divergence analysis marks it divergent.
    // It is uniform by construction; pin it to an SGPR so j-loads scalarize.
    IT = __builtin_amdgcn_readfirstlane(IT);
    int jt = 4 * IT + (bid - (IT * (Tj + 2) - 2 * IT * IT));   // uniform (SGPR math)

    int my_it = 4 * IT + wid;        // this wave's i-tile
    int i     = my_it * JT + lane;
    int jbase = jt * JT;             // uniform

    const float2* pos2  = (const float2*)pos;
    const float2* size2 = (const float2*)size;

    // This wave's i-box (v_i folded in after the loop).
    float xi = 0.f, yi = 0.f, hwi = 0.f, hhi = 0.f, aie = EPSf, vi = 0.f;
    if (i < n) {
        float2 p = pos2[i];
        float2 s = size2[i];
        xi = p.x;  yi = p.y;
        hwi = 0.5f * s.x;  hhi = 0.5f * s.y;
        aie = s.x * s.y + EPSf;
        vi = valid[i];
    }

    float s_iou = 0.f, s_rep = 0.f;
    if (jt > my_it)
        inner_loop<false>(A + jbase, lane, xi, yi, hwi, hhi, aie, s_iou, s_rep);
    else if (jt == my_it)
        inner_loop<true >(A + jbase, lane, xi, yi, hwi, hhi, aie, s_iou, s_rep);
    // jt < my_it: this wave's pairs are covered by another block -> contribute 0.

    s_iou *= vi;
    s_rep *= vi;
    for (int off = 32; off > 0; off >>= 1) {
        s_iou += __shfl_down(s_iou, off);
        s_rep += __shfl_down(s_rep, off);
    }
    if (lane == 0) { red_i[wid] = s_iou; red_r[wid] = s_rep; }
    __syncthreads();
    if (tid == 0) {
        part[bid]     = (red_i[0] + red_i[1]) + (red_i[2] + red_i[3]);
        part[P + bid] = (red_r[0] + red_r[1]) + (red_r[2] + red_r[3]);
    }
}

__global__ __launch_bounds__(256) void ol_finalize(
    const float* __restrict__ part, int P,
    const float* __restrict__ valid, int n, float* __restrict__ out)
{
    int tid = (int)threadIdx.x;
    double a = 0.0, b = 0.0, S = 0.0, Q = 0.0;
    for (int k = tid; k < P; k += 256) {
        a += (double)part[k];
        b += (double)part[P + k];
    }
    for (int k = tid; k < n; k += 256) {
        double v = (double)valid[k];
        S += v;
        Q += v * v;
    }
    for (int off = 32; off > 0; off >>= 1) {
        a += __shfl_down(a, off);
        b += __shfl_down(b, off);
        S += __shfl_down(S, off);
        Q += __shfl_down(Q, off);
    }
    __shared__ double red[4][4];
    int lane = tid & 63, wid = tid >> 6;
    if (lane == 0) { red[0][wid] = a; red[1][wid] = b; red[2][wid] = S; red[3][wid] = Q; }
    __syncthreads();
    if (tid == 0) {
        a = red[0][0] + red[0][1] + red[0][2] + red[0][3];
        b = red[1][0] + red[1][1] + red[1][2] + red[1][3];
        S = red[2][0] + red[2][1] + red[2][2] + red[2][3];
        Q = red[3][0] + red[3][1] + red[3][2] + red[3][3];
        double denom = 0.5 * (S * S - Q) + 1e-6;            // sum_{i<j} v_i v_j + EPS
        out[0] = (float)(0.5 * ((a + b) / denom));          // WEIGHT * RAMP = 0.5
    }
}

extern "C" void kernel_launch(void* const* d_in, const int* in_sizes, int n_in,
                              void* d_out, int out_size, void* d_ws, size_t ws_size,
                              hipStream_t stream) {
    const float* pos   = (const float*)d_in[0];
    const float* size  = (const float*)d_in[1];
    const float* valid = (const float*)d_in[2];
    float* out = (float*)d_out;

    int n     = in_sizes[2];                 // valid_mask length = N
    int Tj    = (n + JT - 1) / JT;           // 128 j-tiles
    int total = Tj * JT;                     // padded j-slot count
    int Ti    = (Tj + 3) / 4;                // 32 i-groups (4 i-tiles each)
    int P     = Ti * (Tj + 2) - 2 * Ti * Ti; // 2112 blocks

    // ws layout: A[total] (float4) | part[2P] (float)
    float4* A   = (float4*)d_ws;
    float*  prt = (float*)((char*)d_ws + (size_t)total * 16);

    ol_prep<<<(total + 255) / 256, 256, 0, stream>>>(pos, size, valid, A, n, total);
    ol_pair_kernel<<<P, BT, 0, stream>>>(pos, size, valid, A, prt, n, Tj, P);
    ol_finalize<<<1, 256, 0, stream>>>(prt, P, valid, n, out);
}

// Round 15
// 35.835 us; speedup vs baseline: 1.1839x; 1.1839x over previous
//
#include <hip/hip_runtime.h>

#define BT 256           // threads per block = 4 waves
#define JT 64            // j-tile width; each wave owns one 64-row i-tile
#define FARV 1.0e7f

template<bool DIAG>
__device__ __forceinline__ void inner_loop(
    const float4* __restrict__ sh_a,
    int lane, float xi, float yi, float hwi, float hhi, float aie,
    float& s_iou, float& s_rep)
{
    const float EPSf = 1e-6f;
    #pragma unroll 8
    for (int t = 0; t < JT; ++t) {
        float4 a = sh_a[t];      // xj, yj, hwj, hhj (broadcast LDS read)

        float dx = xi - a.x;
        float dy = yi - a.y;
        if (DIAG) dx = (t > lane) ? dx : FARV;   // kills both terms for j<=i

        // 1-D overlap: (h1+h2) - max(|dx|, |h1-h2|), clamped at 0.
        float iw = fmaxf((hwi + a.z) - fmaxf(fabsf(dx), fabsf(hwi - a.z)), 0.f);
        float ih = fmaxf((hhi + a.w) - fmaxf(fabsf(dy), fabsf(hhi - a.w)), 0.f);
        float inter = iw * ih;
        // union = area_i + EPS + 4*hwj*hhj - inter   (area_j = 4*hwj*hhj)
        float uni = fmaf(4.f * a.z, a.w, aie - inter);   // >= EPS
        float rc  = __builtin_amdgcn_rcpf(uni);
        s_iou = fmaf(inter, rc, s_iou);

        float d2 = fmaf(dx, dx, fmaf(dy, dy, EPSf));
        if (__any(d2 < 0.0036f)) {               // any lane within repel radius?
            float dist = __builtin_amdgcn_sqrtf(d2);
            float rp   = fmaxf(0.06f - dist, 0.f);
            s_rep = fmaf(rp, rp, s_rep);
        }
    }
}

__global__ __launch_bounds__(BT) void ol_pair_kernel(
    const float* __restrict__ pos, const float* __restrict__ size,
    const float* __restrict__ valid, float* __restrict__ part,
    int n, int Tj, int P)
{
    __shared__ float4 sh_a[JT];
    __shared__ float  red_i[4], red_r[4];

    const float EPSf = 1e-6f;
    int tid  = (int)threadIdx.x;
    int lane = tid & 63;
    int wid  = tid >> 6;
    int bid  = (int)blockIdx.x;

    // Decode bid -> (IT, jt): i-group IT covers i-tiles 4IT..4IT+3, j-tiles jt >= 4IT.
    // C(r) = r*(Tj+2) - 2r^2 blocks precede group r.
    float Bf = (float)(Tj + 2);
    float disc = Bf * Bf - 8.f * (float)bid;
    int IT = (int)((Bf - sqrtf(fmaxf(disc, 0.f))) * 0.25f);
    IT = max(0, IT);
    while ((IT + 1) * (Tj + 2) - 2 * (IT + 1) * (IT + 1) <= bid) ++IT;
    while (IT > 0 && IT * (Tj + 2) - 2 * IT * IT > bid) --IT;
    int jt = 4 * IT + (bid - (IT * (Tj + 2) - 2 * IT * IT));

    int my_it = 4 * IT + wid;        // this wave's i-tile
    int i     = my_it * JT + lane;
    int jbase = jt * JT;

    const float2* pos2  = (const float2*)pos;
    const float2* size2 = (const float2*)size;

    // Stage j-tile: invalid/pad boxes pushed to FARV so both terms vanish.
    if (tid < JT) {
        int j = jbase + tid;
        float xj = FARV, yj = FARV, hwj = 0.f, hhj = 0.f;
        if (j < n) {
            float2 p = pos2[j];
            float2 s = size2[j];
            hwj = 0.5f * s.x;  hhj = 0.5f * s.y;
            if (valid[j] != 0.f) { xj = p.x; yj = p.y; }
        }
        sh_a[tid] = make_float4(xj, yj, hwj, hhj);
    }

    // This wave's i-box (v_i folded in after the loop).
    float xi = 0.f, yi = 0.f, hwi = 0.f, hhi = 0.f, aie = EPSf, vi = 0.f;
    if (i < n) {
        float2 p = pos2[i];
        float2 s = size2[i];
        xi = p.x;  yi = p.y;
        hwi = 0.5f * s.x;  hhi = 0.5f * s.y;
        aie = s.x * s.y + EPSf;
        vi = valid[i];
    }
    __syncthreads();

    float s_iou = 0.f, s_rep = 0.f;
    if (jt > my_it)
        inner_loop<false>(sh_a, lane, xi, yi, hwi, hhi, aie, s_iou, s_rep);
    else if (jt == my_it)
        inner_loop<true >(sh_a, lane, xi, yi, hwi, hhi, aie, s_iou, s_rep);
    // jt < my_it: this wave's pairs are covered by another block -> contribute 0.

    s_iou *= vi;
    s_rep *= vi;
    for (int off = 32; off > 0; off >>= 1) {
        s_iou += __shfl_down(s_iou, off);
        s_rep += __shfl_down(s_rep, off);
    }
    if (lane == 0) { red_i[wid] = s_iou; red_r[wid] = s_rep; }
    __syncthreads();
    if (tid == 0) {
        part[bid]     = (red_i[0] + red_i[1]) + (red_i[2] + red_i[3]);
        part[P + bid] = (red_r[0] + red_r[1]) + (red_r[2] + red_r[3]);
    }
}

__global__ __launch_bounds__(256) void ol_finalize(
    const float* __restrict__ part, int P,
    const float* __restrict__ valid, int n, float* __restrict__ out)
{
    int tid = (int)threadIdx.x;
    double a = 0.0, b = 0.0, S = 0.0, Q = 0.0;
    for (int k = tid; k < P; k += 256) {
        a += (double)part[k];
        b += (double)part[P + k];
    }
    for (int k = tid; k < n; k += 256) {
        double v = (double)valid[k];
        S += v;
        Q += v * v;
    }
    for (int off = 32; off > 0; off >>= 1) {
        a += __shfl_down(a, off);
        b += __shfl_down(b, off);
        S += __shfl_down(S, off);
        Q += __shfl_down(Q, off);
    }
    __shared__ double red[4][4];
    int lane = tid & 63, wid = tid >> 6;
    if (lane == 0) { red[0][wid] = a; red[1][wid] = b; red[2][wid] = S; red[3][wid] = Q; }
    __syncthreads();
    if (tid == 0) {
        a = red[0][0] + red[0][1] + red[0][2] + red[0][3];
        b = red[1][0] + red[1][1] + red[1][2] + red[1][3];
        S = red[2][0] + red[2][1] + red[2][2] + red[2][3];
        Q = red[3][0] + red[3][1] + red[3][2] + red[3][3];
        double denom = 0.5 * (S * S - Q) + 1e-6;            // sum_{i<j} v_i v_j + EPS
        out[0] = (float)(0.5 * ((a + b) / denom));          // WEIGHT * RAMP = 0.5
    }
}

extern "C" void kernel_launch(void* const* d_in, const int* in_sizes, int n_in,
                              void* d_out, int out_size, void* d_ws, size_t ws_size,
                              hipStream_t stream) {
    const float* pos   = (const float*)d_in[0];
    const float* size  = (const float*)d_in[1];
    const float* valid = (const float*)d_in[2];
    float* out = (float*)d_out;
    float* ws  = (float*)d_ws;
    int n  = in_sizes[2];                    // valid_mask length = N
    int Tj = (n + JT - 1) / JT;              // 128 j-tiles
    int Ti = (Tj + 3) / 4;                   // 32 i-groups (4 i-tiles each)
    int P  = Ti * (Tj + 2) - 2 * Ti * Ti;    // 2112 blocks

    ol_pair_kernel<<<P, BT, 0, stream>>>(pos, size, valid, ws, n, Tj, P);
    ol_finalize<<<1, 256, 0, stream>>>(ws, P, valid, n, out);
}